// Round 1
// 217.471 us; speedup vs baseline: 1.0605x; 1.0605x over previous
//
#include <hip/hip_runtime.h>
#include <hip/hip_fp16.h>

// Problem constants (match reference):
//   attrs:    [8, 10000, 3, 16] fp32   (flat face table of 80000 faces x 48 floats)
//   baryw:    [8, 512, 512, 3]  fp32
//   triangle: [8, 512, 512]     int32  (-1 = background; indexes flat [BZ*NF])
//   out:      [8, 17, 512, 512] fp32   (16 interpolated channels + visibility)
//
// R3 strategy: the R2 counters showed ~131 MB of gather *fill* traffic for a
// 10.24 MB table -> L2 capacity misses (table > 4 MB per-XCD L2), each served
// from L3 at long latency. Fix: PHASE the gather by face range. 4 phases of
// 20000 faces (2.56 MB of records each) fit L2; threads accumulate their
// pixels only in the phase owning their face, with __syncthreads() keeping
// the block's waves phase-coherent. Output stores + streamed tri/baryw are
// nontemporal so the 142.6 MB write stream doesn't evict the hot table range.
constexpr int BZ = 8, NF = 10000, D = 16, HImg = 512, WImg = 512;
constexpr int HW = HImg * WImg;          // 262144
constexpr int NPIX = BZ * HW;            // 2097152
constexpr int NFACES = BZ * NF;          // 80000
constexpr int PIX_PER_THREAD = 4;
constexpr int NTHREADS = NPIX / PIX_PER_THREAD;  // 524288
constexpr int BLOCK = 256;
// fp16 record: 3 vertices x 16 ch x 2 B = 96 B, padded to 128 B (one line).
constexpr size_t REC_USHORTS = 64;       // 128 B / 2
constexpr size_t WS_NEEDED = (size_t)NFACES * 128;

constexpr int NPHASE = 4;
constexpr int FACES_PER_PHASE = NFACES / NPHASE;  // 20000 -> 2.56 MB/phase

typedef float f32x4 __attribute__((ext_vector_type(4)));
typedef int   i32x4 __attribute__((ext_vector_type(4)));

// ---- pass 1: fp32 attrs -> fp16 padded records --------------------------
// 6 chunks of 8 values per face; source offset face*48 + c*8 (linear),
// dest offset face*64 + c*8 (pad lives at the tail of each record).
__global__ __launch_bounds__(BLOCK) void convert_kernel(
    const float* __restrict__ attrs, ushort* __restrict__ rec)
{
    const int tid = blockIdx.x * BLOCK + threadIdx.x;
    if (tid >= NFACES * 6) return;
    const int face = tid / 6;
    const int c    = tid - face * 6;
    const float4* src = reinterpret_cast<const float4*>(
        attrs + (size_t)face * 48 + c * 8);
    const float4 a = src[0], b = src[1];
    __half h[8];
    h[0] = __float2half_rn(a.x); h[1] = __float2half_rn(a.y);
    h[2] = __float2half_rn(a.z); h[3] = __float2half_rn(a.w);
    h[4] = __float2half_rn(b.x); h[5] = __float2half_rn(b.y);
    h[6] = __float2half_rn(b.z); h[7] = __float2half_rn(b.w);
    *reinterpret_cast<int4*>(rec + (size_t)face * REC_USHORTS + c * 8) =
        *reinterpret_cast<const int4*>(h);
}

__device__ inline void h8_to_f8(int4 raw, float f[8]) {
    const __half2* hp = reinterpret_cast<const __half2*>(&raw);
#pragma unroll
    for (int q = 0; q < 4; ++q) {
        const float2 t = __half22float2(hp[q]);
        f[2 * q]     = t.x;
        f[2 * q + 1] = t.y;
    }
}

// ---- pass 2: phased render from fp16 records ----------------------------
__global__ __launch_bounds__(BLOCK) void render_f16_phased_kernel(
    const ushort* __restrict__ rec,
    const float*  __restrict__ baryw,
    const int*    __restrict__ tri,
    float*        __restrict__ out)
{
    // grid exactly covers NPIX: no early returns -> __syncthreads() is safe.
    const int tid = blockIdx.x * BLOCK + threadIdx.x;
    const int p0  = tid * PIX_PER_THREAD;

    const int n   = p0 / HW;
    const int pix = p0 - n * HW;

    // Streamed inputs: nontemporal so they don't evict the face table in L2.
    const i32x4 t4 = __builtin_nontemporal_load(
        reinterpret_cast<const i32x4*>(tri + p0));
    const f32x4* bw = reinterpret_cast<const f32x4*>(baryw + (size_t)p0 * 3);
    const f32x4 b0 = __builtin_nontemporal_load(bw + 0);
    const f32x4 b1 = __builtin_nontemporal_load(bw + 1);
    const f32x4 b2 = __builtin_nontemporal_load(bw + 2);

    float w[PIX_PER_THREAD][3] = {
        {b0.x, b0.y, b0.z},
        {b0.w, b1.x, b1.y},
        {b1.z, b1.w, b2.x},
        {b2.y, b2.z, b2.w},
    };
    const int t[PIX_PER_THREAD] = {t4.x, t4.y, t4.z, t4.w};

    float vis[PIX_PER_THREAD];
#pragma unroll
    for (int j = 0; j < PIX_PER_THREAD; ++j) {
        const bool bg = (t[j] < 0);
        vis[j] = bg ? 0.0f : 1.0f;
        // bg pixels never match any phase range (unsigned compare vs -1),
        // so their accumulators stay exactly 0; no weight masking needed,
        // but keep it for bit-identical behavior on denormal-ish inputs.
        w[j][0] *= vis[j];
        w[j][1] *= vis[j];
        w[j][2] *= vis[j];
    }

    const size_t outbase = (size_t)n * (D + 1) * HW + pix;
    const int4* rec4 = reinterpret_cast<const int4*>(rec);

    // two chunks of 8 channels; per chunk, sweep 4 face-range phases.
#pragma unroll
    for (int c = 0; c < 2; ++c) {
        float r[PIX_PER_THREAD][8];
#pragma unroll
        for (int j = 0; j < PIX_PER_THREAD; ++j)
#pragma unroll
            for (int i = 0; i < 8; ++i) r[j][i] = 0.0f;

#pragma unroll
        for (int ph = 0; ph < NPHASE; ++ph) {
            const int lo = ph * FACES_PER_PHASE;
#pragma unroll
            for (int j = 0; j < PIX_PER_THREAD; ++j) {
                // in-range test; t[j] == -1 wraps to huge unsigned -> false
                if ((unsigned)(t[j] - lo) < (unsigned)FACES_PER_PHASE) {
                    const int4* rb = rec4 + (size_t)t[j] * 8;
                    const int4 A0 = rb[0 + c];   // vertex 0, chans 8c..8c+7
                    const int4 A1 = rb[2 + c];   // vertex 1
                    const int4 A2 = rb[4 + c];   // vertex 2
                    float a0[8], a1[8], a2[8];
                    h8_to_f8(A0, a0);
                    h8_to_f8(A1, a1);
                    h8_to_f8(A2, a2);
#pragma unroll
                    for (int i = 0; i < 8; ++i)
                        r[j][i] += w[j][0] * a0[i] + w[j][1] * a1[i]
                                 + w[j][2] * a2[i];
                }
            }
            // keep the block's waves phase-coherent so machine-wide only one
            // 2.56 MB face range is live in L2 at a time
            if (ph != NPHASE - 1) __syncthreads();
        }

#pragma unroll
        for (int i = 0; i < 8; ++i) {
            const int d = c * 8 + i;
            f32x4 o;
            o.x = r[0][i]; o.y = r[1][i]; o.z = r[2][i]; o.w = r[3][i];
            __builtin_nontemporal_store(
                o, reinterpret_cast<f32x4*>(out + outbase + (size_t)d * HW));
        }
        if (c == 0) __syncthreads();
    }

    f32x4 v;
    v.x = vis[0]; v.y = vis[1]; v.z = vis[2]; v.w = vis[3];
    __builtin_nontemporal_store(
        v, reinterpret_cast<f32x4*>(out + outbase + (size_t)D * HW));
}

// ---- fallback: direct fp32 path (R1 kernel) -----------------------------
__global__ __launch_bounds__(BLOCK) void renderer_f32_kernel(
    const float* __restrict__ attrs,
    const float* __restrict__ baryw,
    const int*   __restrict__ tri,
    float*       __restrict__ out)
{
    const int tid = blockIdx.x * BLOCK + threadIdx.x;
    const int p0  = tid * PIX_PER_THREAD;
    if (p0 >= NPIX) return;

    const int n   = p0 / HW;
    const int pix = p0 - n * HW;

    const int4 t4 = *reinterpret_cast<const int4*>(tri + p0);
    const float4* bw = reinterpret_cast<const float4*>(baryw + (size_t)p0 * 3);
    const float4 b0 = bw[0], b1 = bw[1], b2 = bw[2];

    float w[PIX_PER_THREAD][3] = {
        {b0.x, b0.y, b0.z},
        {b0.w, b1.x, b1.y},
        {b1.z, b1.w, b2.x},
        {b2.y, b2.z, b2.w},
    };
    const int t[PIX_PER_THREAD] = {t4.x, t4.y, t4.z, t4.w};

    float vis[PIX_PER_THREAD];
    const float4* abase[PIX_PER_THREAD];
#pragma unroll
    for (int j = 0; j < PIX_PER_THREAD; ++j) {
        const bool bg = (t[j] < 0);
        vis[j] = bg ? 0.0f : 1.0f;
        const int tc = bg ? 0 : t[j];
        abase[j] = reinterpret_cast<const float4*>(attrs + (size_t)tc * (3 * D));
        w[j][0] *= vis[j];
        w[j][1] *= vis[j];
        w[j][2] *= vis[j];
    }

    const size_t outbase = (size_t)n * (D + 1) * HW + pix;

#pragma unroll
    for (int c = 0; c < 4; ++c) {
        float r[PIX_PER_THREAD][4];
#pragma unroll
        for (int j = 0; j < PIX_PER_THREAD; ++j) {
            const float4 a0 = abase[j][c];
            const float4 a1 = abase[j][4 + c];
            const float4 a2 = abase[j][8 + c];
            r[j][0] = w[j][0] * a0.x + w[j][1] * a1.x + w[j][2] * a2.x;
            r[j][1] = w[j][0] * a0.y + w[j][1] * a1.y + w[j][2] * a2.y;
            r[j][2] = w[j][0] * a0.z + w[j][1] * a1.z + w[j][2] * a2.z;
            r[j][3] = w[j][0] * a0.w + w[j][1] * a1.w + w[j][2] * a2.w;
        }
#pragma unroll
        for (int i = 0; i < 4; ++i) {
            const int d = c * 4 + i;
            float4 o;
            o.x = r[0][i]; o.y = r[1][i]; o.z = r[2][i]; o.w = r[3][i];
            *reinterpret_cast<float4*>(out + outbase + (size_t)d * HW) = o;
        }
    }

    float4 v;
    v.x = vis[0]; v.y = vis[1]; v.z = vis[2]; v.w = vis[3];
    *reinterpret_cast<float4*>(out + outbase + (size_t)D * HW) = v;
}

extern "C" void kernel_launch(void* const* d_in, const int* in_sizes, int n_in,
                              void* d_out, int out_size, void* d_ws, size_t ws_size,
                              hipStream_t stream) {
    const float* attrs = (const float*)d_in[0];
    const float* baryw = (const float*)d_in[1];
    const int*   tri   = (const int*)d_in[2];
    float*       out   = (float*)d_out;

    const int grid = NTHREADS / BLOCK;  // 2048 blocks

    if (ws_size >= WS_NEEDED) {
        ushort* rec = (ushort*)d_ws;
        const int conv_grid = (NFACES * 6 + BLOCK - 1) / BLOCK;  // 1875
        convert_kernel<<<conv_grid, BLOCK, 0, stream>>>(attrs, rec);
        render_f16_phased_kernel<<<grid, BLOCK, 0, stream>>>(rec, baryw, tri, out);
    } else {
        renderer_f32_kernel<<<grid, BLOCK, 0, stream>>>(attrs, baryw, tri, out);
    }
}

// Round 2
// 206.834 us; speedup vs baseline: 1.1150x; 1.0514x over previous
//
#include <hip/hip_runtime.h>
#include <hip/hip_fp16.h>

// Problem constants (match reference):
//   attrs:    [8, 10000, 3, 16] fp32   (flat face table of 80000 faces x 48 floats)
//   baryw:    [8, 512, 512, 3]  fp32
//   triangle: [8, 512, 512]     int32  (-1 = background; indexes flat [BZ*NF])
//   out:      [8, 17, 512, 512] fp32   (16 interpolated channels + visibility)
//
// R4 strategy: R3's phasing helped (87.5 -> ~74 us) but time stopped scaling
// with fetch bytes -> the limiter is random-gather REQUEST RATE, not HBM BW.
// The 2-chunk loop gathered each pixel's 96 B record twice (L1 can't hold the
// lines across the store burst + syncthreads between chunks): ~8.4M line
// requests. Fix: SINGLE SWEEP - load all 6 int4 of the record once, keep all
// 16 fp32 accumulators in registers (PIX_PER_THREAD=4 -> 64 acc VGPRs,
// __launch_bounds__(256,4) caps at 128 VGPR / 4 waves/SIMD), and defer ALL
// output stores until after the phase loop so the store stream never evicts
// the hot 2.56 MB face range mid-sweep. Halves line requests and per-XCD
// table refill.
constexpr int BZ = 8, NF = 10000, D = 16, HImg = 512, WImg = 512;
constexpr int HW = HImg * WImg;          // 262144
constexpr int NPIX = BZ * HW;            // 2097152
constexpr int NFACES = BZ * NF;          // 80000
constexpr int PIX_PER_THREAD = 4;
constexpr int NTHREADS = NPIX / PIX_PER_THREAD;  // 524288
constexpr int BLOCK = 256;
// fp16 record: 3 vertices x 16 ch x 2 B = 96 B, padded to 128 B (one line).
constexpr size_t REC_USHORTS = 64;       // 128 B / 2
constexpr size_t WS_NEEDED = (size_t)NFACES * 128;

constexpr int NPHASE = 4;
constexpr int FACES_PER_PHASE = NFACES / NPHASE;  // 20000 -> 2.56 MB/phase

typedef float f32x4 __attribute__((ext_vector_type(4)));
typedef int   i32x4 __attribute__((ext_vector_type(4)));

// ---- pass 1: fp32 attrs -> fp16 padded records --------------------------
// 6 chunks of 8 values per face; source offset face*48 + c*8 (linear),
// dest offset face*64 + c*8 (pad lives at the tail of each record).
__global__ __launch_bounds__(BLOCK) void convert_kernel(
    const float* __restrict__ attrs, ushort* __restrict__ rec)
{
    const int tid = blockIdx.x * BLOCK + threadIdx.x;
    if (tid >= NFACES * 6) return;
    const int face = tid / 6;
    const int c    = tid - face * 6;
    const float4* src = reinterpret_cast<const float4*>(
        attrs + (size_t)face * 48 + c * 8);
    const float4 a = src[0], b = src[1];
    __half h[8];
    h[0] = __float2half_rn(a.x); h[1] = __float2half_rn(a.y);
    h[2] = __float2half_rn(a.z); h[3] = __float2half_rn(a.w);
    h[4] = __float2half_rn(b.x); h[5] = __float2half_rn(b.y);
    h[6] = __float2half_rn(b.z); h[7] = __float2half_rn(b.w);
    *reinterpret_cast<int4*>(rec + (size_t)face * REC_USHORTS + c * 8) =
        *reinterpret_cast<const int4*>(h);
}

__device__ inline void h8_to_f8(int4 raw, float f[8]) {
    const __half2* hp = reinterpret_cast<const __half2*>(&raw);
#pragma unroll
    for (int q = 0; q < 4; ++q) {
        const float2 t = __half22float2(hp[q]);
        f[2 * q]     = t.x;
        f[2 * q + 1] = t.y;
    }
}

// ---- pass 2: phased single-sweep render ---------------------------------
__global__ __launch_bounds__(BLOCK, 4) void render_f16_sweep_kernel(
    const ushort* __restrict__ rec,
    const float*  __restrict__ baryw,
    const int*    __restrict__ tri,
    float*        __restrict__ out)
{
    // grid exactly covers NPIX: no early returns -> __syncthreads() is safe.
    const int tid = blockIdx.x * BLOCK + threadIdx.x;
    const int p0  = tid * PIX_PER_THREAD;

    const int n   = p0 / HW;
    const int pix = p0 - n * HW;

    // Streamed inputs: nontemporal so they don't evict the face table in L2.
    const i32x4 t4 = __builtin_nontemporal_load(
        reinterpret_cast<const i32x4*>(tri + p0));
    const f32x4* bw = reinterpret_cast<const f32x4*>(baryw + (size_t)p0 * 3);
    const f32x4 b0 = __builtin_nontemporal_load(bw + 0);
    const f32x4 b1 = __builtin_nontemporal_load(bw + 1);
    const f32x4 b2 = __builtin_nontemporal_load(bw + 2);

    float w[PIX_PER_THREAD][3] = {
        {b0.x, b0.y, b0.z},
        {b0.w, b1.x, b1.y},
        {b1.z, b1.w, b2.x},
        {b2.y, b2.z, b2.w},
    };
    const int t[PIX_PER_THREAD] = {t4.x, t4.y, t4.z, t4.w};

    float vis[PIX_PER_THREAD];
#pragma unroll
    for (int j = 0; j < PIX_PER_THREAD; ++j) {
        const bool bg = (t[j] < 0);
        vis[j] = bg ? 0.0f : 1.0f;
        // bg pixels never match any phase range (unsigned compare vs -1),
        // so their accumulators stay exactly 0.
        w[j][0] *= vis[j];
        w[j][1] *= vis[j];
        w[j][2] *= vis[j];
    }

    const int4* rec4 = reinterpret_cast<const int4*>(rec);

    float r[PIX_PER_THREAD][D];
#pragma unroll
    for (int j = 0; j < PIX_PER_THREAD; ++j)
#pragma unroll
        for (int i = 0; i < D; ++i) r[j][i] = 0.0f;

    // sweep 4 face-range phases; each pixel's record is read exactly ONCE.
#pragma unroll
    for (int ph = 0; ph < NPHASE; ++ph) {
        const int lo = ph * FACES_PER_PHASE;
#pragma unroll
        for (int j = 0; j < PIX_PER_THREAD; ++j) {
            // in-range test; t[j] == -1 wraps to huge unsigned -> false
            if ((unsigned)(t[j] - lo) < (unsigned)FACES_PER_PHASE) {
                const int4* rb = rec4 + (size_t)t[j] * 8;
                // record layout: vertex k occupies int4 slots [2k, 2k+1]
                const int4 V0 = rb[0];   // v0 ch0-7
                const int4 V1 = rb[1];   // v0 ch8-15
                const int4 V2 = rb[2];   // v1 ch0-7
                const int4 V3 = rb[3];   // v1 ch8-15
                const int4 V4 = rb[4];   // v2 ch0-7
                const int4 V5 = rb[5];   // v2 ch8-15
                float a0[8], a1[8], a2[8], a3[8], a4[8], a5[8];
                h8_to_f8(V0, a0); h8_to_f8(V1, a1);
                h8_to_f8(V2, a2); h8_to_f8(V3, a3);
                h8_to_f8(V4, a4); h8_to_f8(V5, a5);
#pragma unroll
                for (int i = 0; i < 8; ++i) {
                    r[j][i]     += w[j][0] * a0[i] + w[j][1] * a2[i]
                                 + w[j][2] * a4[i];
                    r[j][8 + i] += w[j][0] * a1[i] + w[j][1] * a3[i]
                                 + w[j][2] * a5[i];
                }
            }
        }
        // keep the block's waves phase-coherent so machine-wide only one
        // 2.56 MB face range is live in L2 at a time
        if (ph != NPHASE - 1) __syncthreads();
    }

    // deferred store burst: all 17 channels after the gather phases.
    const size_t outbase = (size_t)n * (D + 1) * HW + pix;
#pragma unroll
    for (int d = 0; d < D; ++d) {
        f32x4 o;
        o.x = r[0][d]; o.y = r[1][d]; o.z = r[2][d]; o.w = r[3][d];
        __builtin_nontemporal_store(
            o, reinterpret_cast<f32x4*>(out + outbase + (size_t)d * HW));
    }
    f32x4 v;
    v.x = vis[0]; v.y = vis[1]; v.z = vis[2]; v.w = vis[3];
    __builtin_nontemporal_store(
        v, reinterpret_cast<f32x4*>(out + outbase + (size_t)D * HW));
}

// ---- fallback: direct fp32 path (R1 kernel) -----------------------------
__global__ __launch_bounds__(BLOCK) void renderer_f32_kernel(
    const float* __restrict__ attrs,
    const float* __restrict__ baryw,
    const int*   __restrict__ tri,
    float*       __restrict__ out)
{
    const int tid = blockIdx.x * BLOCK + threadIdx.x;
    const int p0  = tid * PIX_PER_THREAD;
    if (p0 >= NPIX) return;

    const int n   = p0 / HW;
    const int pix = p0 - n * HW;

    const int4 t4 = *reinterpret_cast<const int4*>(tri + p0);
    const float4* bw = reinterpret_cast<const float4*>(baryw + (size_t)p0 * 3);
    const float4 b0 = bw[0], b1 = bw[1], b2 = bw[2];

    float w[PIX_PER_THREAD][3] = {
        {b0.x, b0.y, b0.z},
        {b0.w, b1.x, b1.y},
        {b1.z, b1.w, b2.x},
        {b2.y, b2.z, b2.w},
    };
    const int t[PIX_PER_THREAD] = {t4.x, t4.y, t4.z, t4.w};

    float vis[PIX_PER_THREAD];
    const float4* abase[PIX_PER_THREAD];
#pragma unroll
    for (int j = 0; j < PIX_PER_THREAD; ++j) {
        const bool bg = (t[j] < 0);
        vis[j] = bg ? 0.0f : 1.0f;
        const int tc = bg ? 0 : t[j];
        abase[j] = reinterpret_cast<const float4*>(attrs + (size_t)tc * (3 * D));
        w[j][0] *= vis[j];
        w[j][1] *= vis[j];
        w[j][2] *= vis[j];
    }

    const size_t outbase = (size_t)n * (D + 1) * HW + pix;

#pragma unroll
    for (int c = 0; c < 4; ++c) {
        float r[PIX_PER_THREAD][4];
#pragma unroll
        for (int j = 0; j < PIX_PER_THREAD; ++j) {
            const float4 a0 = abase[j][c];
            const float4 a1 = abase[j][4 + c];
            const float4 a2 = abase[j][8 + c];
            r[j][0] = w[j][0] * a0.x + w[j][1] * a1.x + w[j][2] * a2.x;
            r[j][1] = w[j][0] * a0.y + w[j][1] * a1.y + w[j][2] * a2.y;
            r[j][2] = w[j][0] * a0.z + w[j][1] * a1.z + w[j][2] * a2.z;
            r[j][3] = w[j][0] * a0.w + w[j][1] * a1.w + w[j][2] * a2.w;
        }
#pragma unroll
        for (int i = 0; i < 4; ++i) {
            const int d = c * 4 + i;
            float4 o;
            o.x = r[0][i]; o.y = r[1][i]; o.z = r[2][i]; o.w = r[3][i];
            *reinterpret_cast<float4*>(out + outbase + (size_t)d * HW) = o;
        }
    }

    float4 v;
    v.x = vis[0]; v.y = vis[1]; v.z = vis[2]; v.w = vis[3];
    *reinterpret_cast<float4*>(out + outbase + (size_t)D * HW) = v;
}

extern "C" void kernel_launch(void* const* d_in, const int* in_sizes, int n_in,
                              void* d_out, int out_size, void* d_ws, size_t ws_size,
                              hipStream_t stream) {
    const float* attrs = (const float*)d_in[0];
    const float* baryw = (const float*)d_in[1];
    const int*   tri   = (const int*)d_in[2];
    float*       out   = (float*)d_out;

    const int grid = NTHREADS / BLOCK;  // 2048 blocks

    if (ws_size >= WS_NEEDED) {
        ushort* rec = (ushort*)d_ws;
        const int conv_grid = (NFACES * 6 + BLOCK - 1) / BLOCK;  // 1875
        convert_kernel<<<conv_grid, BLOCK, 0, stream>>>(attrs, rec);
        render_f16_sweep_kernel<<<grid, BLOCK, 0, stream>>>(rec, baryw, tri, out);
    } else {
        renderer_f32_kernel<<<grid, BLOCK, 0, stream>>>(attrs, baryw, tri, out);
    }
}